// Round 2
// baseline (578.040 us; speedup 1.0000x reference)
//
#include <hip/hip_runtime.h>
#include <hip/hip_bf16.h>

#define BB 8
#define CC 64
#define HH 256
#define WW 256

__device__ __forceinline__ unsigned short f2bf(float f) {
    __hip_bfloat16 h = __float2bfloat16(f);   // RNE
    return *reinterpret_cast<unsigned short*>(&h);
}
__device__ __forceinline__ float bf2f(unsigned short u) {
    unsigned int v = ((unsigned int)u) << 16;
    float r;
    __builtin_memcpy(&r, &v, 4);
    return r;
}

// ---------------------------------------------------------------------------
// K1: fused 5x5 depthwise (pad 2) + 1x21 horizontal depthwise (pad 10)
// block = (strip of 8 rows) x (b,c). 512 threads: wave w -> row w, lane l -> cols 4l..4l+3
// Horizontal pass done via wave shuffles (no LDS round-trip -> no 8-way conflicts).
// ---------------------------------------------------------------------------
__global__ __launch_bounds__(512) void k1_local_h(
        const float* __restrict__ x, const float* __restrict__ lw,
        const float* __restrict__ hw, unsigned short* __restrict__ a2out) {
    const int strip = blockIdx.x;          // 0..31
    const int bc    = blockIdx.y;          // 0..511
    const int c     = bc & (CC - 1);
    const int y0    = strip * 8;
    const int tid   = threadIdx.x;
    const int r     = tid >> 6;            // wave index = row in strip
    const int l     = tid & 63;

    __shared__ float xs[12][264];          // rows y0-2..y0+9, col i = global x + 2 (0..259)

    const float* xbase = x + (size_t)bc * HH * WW;
    // staging: wave r stages rows r and r+8 (r<4); stride-1 lanes -> conflict-free
    for (int row = r; row < 12; row += 8) {
        int gy = y0 - 2 + row;
        bool rowok = (unsigned)gy < HH;
        const float* xr = xbase + (rowok ? gy : 0) * WW;
        #pragma unroll
        for (int j = 0; j < 4; ++j) {
            int i = l + 64 * j;            // 0..255
            int gx = i - 2;
            float v = (rowok && gx >= 0) ? xr[gx] : 0.f;   // gx <= 253 < WW always
            xs[row][i] = v;
        }
        if (l < 4) {
            int i = 256 + l;
            int gx = i - 2;                // 254..257
            float v = (rowok && gx < WW) ? xr[gx] : 0.f;
            xs[row][i] = v;
        }
    }
    __syncthreads();

    const float* lwc = lw + c * 25;        // block-uniform -> s_load

    // 5x5 depthwise, outputs cols 4l..4l+3 of row y0+r
    float p[4] = {0.f, 0.f, 0.f, 0.f};
    #pragma unroll
    for (int ky = 0; ky < 5; ++ky) {
        const float4* rp = reinterpret_cast<const float4*>(&xs[r + ky][4 * l]);
        float4 lo = rp[0], hi = rp[1];     // aligned ds_read_b128
        float row[8] = {lo.x, lo.y, lo.z, lo.w, hi.x, hi.y, hi.z, hi.w};
        #pragma unroll
        for (int kx = 0; kx < 5; ++kx) {
            float wv = lwc[ky * 5 + kx];
            #pragma unroll
            for (int j = 0; j < 4; ++j) p[j] = fmaf(wv, row[j + kx], p[j]);
        }
    }

    // gather neighbor lanes' attn1 values: nb[d+3][j] = attn1 col 4(l+d)+j (0 if OOB)
    float nb[7][4];
    #pragma unroll
    for (int d = -3; d <= 3; ++d) {
        if (d == 0) {
            #pragma unroll
            for (int j = 0; j < 4; ++j) nb[3][j] = p[j];
        } else {
            int sl = l + d;
            bool ok = (unsigned)sl < 64u;
            #pragma unroll
            for (int j = 0; j < 4; ++j) {
                float v = __shfl(p[j], ok ? sl : 0);
                nb[d + 3][j] = ok ? v : 0.f;
            }
        }
    }

    // 1x21 horizontal: o[j] = sum_k hw[k] * attn1[4l + j + k - 10]
    float o[4] = {0.f, 0.f, 0.f, 0.f};
    const float* hwc = hw + c * 21;
    #pragma unroll
    for (int k = 0; k < 21; ++k) {
        float wv = hwc[k];
        #pragma unroll
        for (int j = 0; j < 4; ++j) {
            int m  = j + k - 10 + 12;      // 2..25  (compile-time)
            int d  = m >> 2;               // 0..6
            int jj = m & 3;
            o[j] = fmaf(wv, nb[d][jj], o[j]);
        }
    }

    unsigned short* dst = a2out + (size_t)(bc * HH + y0 + r) * WW + 4 * l;
    ushort4 pk;
    pk.x = f2bf(o[0]); pk.y = f2bf(o[1]); pk.z = f2bf(o[2]); pk.w = f2bf(o[3]);
    *reinterpret_cast<ushort4*>(dst) = pk;
}

// ---------------------------------------------------------------------------
// K2a: 21x1 vertical depthwise (pad 10), scatter-into-registers.
// block = (strip of 32 rows) x (b,c). 128 threads, thread = 2 adjacent columns
// (ushort2 loads/stores -> 4B/lane). Taps in SGPRs (block-uniform c).
// ---------------------------------------------------------------------------
__global__ __launch_bounds__(128) void k2a_v(
        const unsigned short* __restrict__ a2, const float* __restrict__ vw,
        unsigned short* __restrict__ a3) {
    const int strip = blockIdx.x;          // 0..7
    const int bc    = blockIdx.y;
    const int c     = bc & (CC - 1);
    const int y0    = strip * 32;
    const int t     = threadIdx.x;         // 0..127 -> cols 2t, 2t+1
    const float* vwc = vw + c * 21;        // s_load

    float accA[32], accB[32];
    #pragma unroll
    for (int i = 0; i < 32; ++i) { accA[i] = 0.f; accB[i] = 0.f; }

    const ushort2* src = reinterpret_cast<const ushort2*>(a2 + (size_t)bc * HH * WW) + t;
    #pragma unroll
    for (int rr = 0; rr < 52; ++rr) {
        int gy = y0 + rr - 10;
        float va = 0.f, vb = 0.f;
        if ((unsigned)gy < HH) {
            ushort2 v = src[gy * (WW / 2)];
            va = bf2f(v.x); vb = bf2f(v.y);
        }
        #pragma unroll
        for (int k = 0; k < 21; ++k) {
            int yl = rr - k;                       // compile-time prune
            if (yl >= 0 && yl < 32) {
                float wv = vwc[k];
                accA[yl] = fmaf(wv, va, accA[yl]);
                accB[yl] = fmaf(wv, vb, accB[yl]);
            }
        }
    }
    ushort2* dst = reinterpret_cast<ushort2*>(a3 + (size_t)bc * HH * WW + (size_t)y0 * WW) + t;
    #pragma unroll
    for (int y = 0; y < 32; ++y) {
        ushort2 o;
        o.x = f2bf(accA[y]); o.y = f2bf(accB[y]);
        dst[y * (WW / 2)] = o;
    }
}

// ---------------------------------------------------------------------------
// K2b: 1x1 pointwise (64x64) + BN + sigmoid gate.
// block = one (b, y) row. 256 threads: wave w -> co 16w..16w+15, lane l -> px 4l..4l+3.
// attn3 row staged bf16 in LDS; pw weights via wave-uniform scalar loads.
// ---------------------------------------------------------------------------
__global__ __launch_bounds__(256) void k2b_pw(
        const unsigned short* __restrict__ a3, const float* __restrict__ x,
        const float* __restrict__ pw, const float* __restrict__ gamma,
        const float* __restrict__ beta, const float* __restrict__ mean,
        const float* __restrict__ var, float* __restrict__ out) {
    const int y   = blockIdx.x;
    const int b   = blockIdx.y;
    const int tid = threadIdx.x;

    __shared__ unsigned short a3s[64][256];   // 32 KB

    const unsigned short* abase = a3 + ((size_t)b * CC * HH + y) * WW;
    for (int i = tid; i < 64 * 64; i += 256) {
        int ci = i >> 6, q = (i & 63) << 2;
        ushort4 v = *reinterpret_cast<const ushort4*>(abase + (size_t)ci * HH * WW + q);
        *reinterpret_cast<ushort4*>(&a3s[ci][q]) = v;
    }
    __syncthreads();

    const int wu = __builtin_amdgcn_readfirstlane(tid >> 6);  // wave-uniform co group
    const int l  = tid & 63;

    float acc[64];
    #pragma unroll
    for (int i = 0; i < 64; ++i) acc[i] = 0.f;

    #pragma unroll 4
    for (int ci = 0; ci < 64; ++ci) {
        ushort4 raw = *reinterpret_cast<const ushort4*>(&a3s[ci][l << 2]);
        float p0 = bf2f(raw.x), p1 = bf2f(raw.y), p2 = bf2f(raw.z), p3 = bf2f(raw.w);
        #pragma unroll
        for (int j = 0; j < 16; ++j) {
            float wv = pw[(wu * 16 + j) * 64 + ci];   // uniform -> s_load
            acc[j * 4 + 0] = fmaf(wv, p0, acc[j * 4 + 0]);
            acc[j * 4 + 1] = fmaf(wv, p1, acc[j * 4 + 1]);
            acc[j * 4 + 2] = fmaf(wv, p2, acc[j * 4 + 2]);
            acc[j * 4 + 3] = fmaf(wv, p3, acc[j * 4 + 3]);
        }
    }

    #pragma unroll
    for (int j = 0; j < 16; ++j) {
        int co = wu * 16 + j;
        float inv = gamma[co] * rsqrtf(var[co] + 1e-5f);
        float sh  = beta[co] - mean[co] * inv;
        size_t off = (((size_t)b * CC + co) * HH + y) * WW + (l << 2);
        float4 xv = *reinterpret_cast<const float4*>(x + off);
        float4 r;
        float a;
        a = acc[j * 4 + 0] * inv + sh; r.x = xv.x / (1.f + __expf(-a));
        a = acc[j * 4 + 1] * inv + sh; r.y = xv.y / (1.f + __expf(-a));
        a = acc[j * 4 + 2] * inv + sh; r.z = xv.z / (1.f + __expf(-a));
        a = acc[j * 4 + 3] * inv + sh; r.w = xv.w / (1.f + __expf(-a));
        *reinterpret_cast<float4*>(out + off) = r;
    }
}

extern "C" void kernel_launch(void* const* d_in, const int* in_sizes, int n_in,
                              void* d_out, int out_size, void* d_ws, size_t ws_size,
                              hipStream_t stream) {
    const float* x     = (const float*)d_in[0];
    const float* lw    = (const float*)d_in[1];
    const float* hw    = (const float*)d_in[2];
    const float* vw    = (const float*)d_in[3];
    const float* pw    = (const float*)d_in[4];
    const float* gamma = (const float*)d_in[5];
    const float* beta  = (const float*)d_in[6];
    const float* mean  = (const float*)d_in[7];
    const float* var   = (const float*)d_in[8];
    float* out = (float*)d_out;

    // ws: attn2 (bf16) + attn3 (bf16) = 2 * 64 MiB = 128 MiB
    unsigned short* ws1 = (unsigned short*)d_ws;
    unsigned short* ws2 = ws1 + (size_t)BB * CC * HH * WW;

    k1_local_h<<<dim3(HH / 8, BB * CC), 512, 0, stream>>>(x, lw, hw, ws1);
    k2a_v<<<dim3(HH / 32, BB * CC), 128, 0, stream>>>(ws1, vw, ws2);
    k2b_pw<<<dim3(HH, BB), 256, 0, stream>>>(ws2, x, pw, gamma, beta, mean, var, out);
}

// Round 3
// 451.862 us; speedup vs baseline: 1.2792x; 1.2792x over previous
//
#include <hip/hip_runtime.h>
#include <hip/hip_bf16.h>

#define BB 8
#define CC 64
#define HH 256
#define WW 256

__device__ __forceinline__ unsigned short f2bf(float f) {
    __hip_bfloat16 h = __float2bfloat16(f);   // RNE
    return *reinterpret_cast<unsigned short*>(&h);
}
__device__ __forceinline__ float bf2f(unsigned short u) {
    unsigned int v = ((unsigned int)u) << 16;
    float r;
    __builtin_memcpy(&r, &v, 4);
    return r;
}

// ---------------------------------------------------------------------------
// K1: fused 5x5 depthwise (pad 2) + 1x21 horizontal depthwise (pad 10)
// block = (strip of 8 rows) x (b,c). 512 threads: wave w -> row w, lane l -> cols 4l..4l+3
// Horizontal pass through LDS with 16B-aligned b128 layout:
//   a1[r][i] = attn1 col (i-12); write at 12+4l (aligned), read 7xfloat4 at 4l.
// Lane-stride-16B b128 is the conflict-free minimum-round LDS pattern.
// ---------------------------------------------------------------------------
__global__ __launch_bounds__(512) void k1_local_h(
        const float* __restrict__ x, const float* __restrict__ lw,
        const float* __restrict__ hw, unsigned short* __restrict__ a2out) {
    const int strip = blockIdx.x;          // 0..31
    const int bc    = blockIdx.y;          // 0..511
    const int c     = bc & (CC - 1);
    const int y0    = strip * 8;
    const int tid   = threadIdx.x;
    const int r     = tid >> 6;            // wave index = row in strip
    const int l     = tid & 63;

    __shared__ float xs[12][264];          // rows y0-2..y0+9, col i = global x + 2 (0..259)
    __shared__ float a1[8][280];           // a1[r][i] = attn1 col (i-12); pads zeroed

    const float* xbase = x + (size_t)bc * HH * WW;
    for (int row = r; row < 12; row += 8) {
        int gy = y0 - 2 + row;
        bool rowok = (unsigned)gy < HH;
        const float* xr = xbase + (rowok ? gy : 0) * WW;
        #pragma unroll
        for (int j = 0; j < 4; ++j) {
            int i = l + 64 * j;            // 0..255
            int gx = i - 2;
            float v = (rowok && gx >= 0) ? xr[gx] : 0.f;   // gx <= 253 < WW always
            xs[row][i] = v;
        }
        if (l < 4) {
            int i = 256 + l;
            int gx = i - 2;                // 254..257
            float v = (rowok && gx < WW) ? xr[gx] : 0.f;
            xs[row][i] = v;
        }
    }
    // zero a1 pad regions: i in [0,12) and [268,280), 8 rows x 24 = 192 entries
    if (tid < 192) {
        int rr = tid / 24, jj = tid - rr * 24;
        a1[rr][jj < 12 ? jj : (256 + jj)] = 0.f;   // jj 12..23 -> 268..279
    }
    __syncthreads();

    const float* lwc = lw + c * 25;        // block-uniform -> s_load

    // 5x5 depthwise, outputs cols 4l..4l+3 of row y0+r
    float p[4] = {0.f, 0.f, 0.f, 0.f};
    #pragma unroll
    for (int ky = 0; ky < 5; ++ky) {
        const float4* rp = reinterpret_cast<const float4*>(&xs[r + ky][4 * l]);
        float4 lo = rp[0], hi = rp[1];     // aligned ds_read_b128, stride-16B
        float row[8] = {lo.x, lo.y, lo.z, lo.w, hi.x, hi.y, hi.z, hi.w};
        #pragma unroll
        for (int kx = 0; kx < 5; ++kx) {
            float wv = lwc[ky * 5 + kx];
            #pragma unroll
            for (int j = 0; j < 4; ++j) p[j] = fmaf(wv, row[j + kx], p[j]);
        }
    }

    // write attn1 (aligned b128), then read back the 28-wide window (7 aligned b128)
    *reinterpret_cast<float4*>(&a1[r][12 + 4 * l]) = make_float4(p[0], p[1], p[2], p[3]);
    __syncthreads();

    float wnd[28];
    const float4* wp = reinterpret_cast<const float4*>(&a1[r][4 * l]);
    #pragma unroll
    for (int q = 0; q < 7; ++q) {
        float4 v = wp[q];
        wnd[4 * q + 0] = v.x; wnd[4 * q + 1] = v.y;
        wnd[4 * q + 2] = v.z; wnd[4 * q + 3] = v.w;
    }

    // o[j] = sum_k hw[k] * attn1[4l + j + k - 10] = sum_k hw[k] * wnd[j + k + 2]
    float o[4] = {0.f, 0.f, 0.f, 0.f};
    const float* hwc = hw + c * 21;
    #pragma unroll
    for (int k = 0; k < 21; ++k) {
        float wv = hwc[k];
        #pragma unroll
        for (int j = 0; j < 4; ++j) o[j] = fmaf(wv, wnd[j + k + 2], o[j]);
    }

    unsigned short* dst = a2out + (size_t)(bc * HH + y0 + r) * WW + 4 * l;
    ushort4 pk;
    pk.x = f2bf(o[0]); pk.y = f2bf(o[1]); pk.z = f2bf(o[2]); pk.w = f2bf(o[3]);
    *reinterpret_cast<ushort4*>(dst) = pk;
}

// ---------------------------------------------------------------------------
// K2a: 21x1 vertical depthwise (pad 10), scatter-into-registers.
// block = (strip of 32 rows) x (b,c). 256 threads = 128 col-pairs x 2 row-halves.
// thread = 2 cols x 16 rows -> 32 fp32 accs (MUST stay <= 32: 64 accs spilled in R2,
// VGPR_Count=52 < accumulator footprint -> scratch thrash, 240us).
// ---------------------------------------------------------------------------
__global__ __launch_bounds__(256) void k2a_v(
        const unsigned short* __restrict__ a2, const float* __restrict__ vw,
        unsigned short* __restrict__ a3) {
    const int strip = blockIdx.x;          // 0..7 (32 rows)
    const int bc    = blockIdx.y;
    const int c     = bc & (CC - 1);
    const int t     = threadIdx.x;
    const int cp    = t & 127;             // column pair -> cols 2cp, 2cp+1
    const int half  = t >> 7;              // 0/1
    const int y0    = strip * 32 + half * 16;
    const float* vwc = vw + c * 21;        // s_load

    float accA[16], accB[16];
    #pragma unroll
    for (int i = 0; i < 16; ++i) { accA[i] = 0.f; accB[i] = 0.f; }

    const ushort2* src = reinterpret_cast<const ushort2*>(a2 + (size_t)bc * HH * WW) + cp;
    #pragma unroll
    for (int rr = 0; rr < 36; ++rr) {
        int gy = y0 + rr - 10;
        float va = 0.f, vb = 0.f;
        if ((unsigned)gy < HH) {
            ushort2 v = src[gy * (WW / 2)];
            va = bf2f(v.x); vb = bf2f(v.y);
        }
        #pragma unroll
        for (int k = 0; k < 21; ++k) {
            int yl = rr - k;                       // compile-time prune
            if (yl >= 0 && yl < 16) {
                float wv = vwc[k];
                accA[yl] = fmaf(wv, va, accA[yl]);
                accB[yl] = fmaf(wv, vb, accB[yl]);
            }
        }
    }
    ushort2* dst = reinterpret_cast<ushort2*>(a3 + (size_t)bc * HH * WW + (size_t)y0 * WW) + cp;
    #pragma unroll
    for (int y = 0; y < 16; ++y) {
        ushort2 o;
        o.x = f2bf(accA[y]); o.y = f2bf(accB[y]);
        dst[y * (WW / 2)] = o;
    }
}

// ---------------------------------------------------------------------------
// K2b: 1x1 pointwise (64x64) + BN + sigmoid gate.  (unchanged this round)
// block = one (b, y) row. 256 threads: wave w -> co 16w..16w+15, lane l -> px 4l..4l+3.
// ---------------------------------------------------------------------------
__global__ __launch_bounds__(256) void k2b_pw(
        const unsigned short* __restrict__ a3, const float* __restrict__ x,
        const float* __restrict__ pw, const float* __restrict__ gamma,
        const float* __restrict__ beta, const float* __restrict__ mean,
        const float* __restrict__ var, float* __restrict__ out) {
    const int y   = blockIdx.x;
    const int b   = blockIdx.y;
    const int tid = threadIdx.x;

    __shared__ unsigned short a3s[64][256];   // 32 KB

    const unsigned short* abase = a3 + ((size_t)b * CC * HH + y) * WW;
    for (int i = tid; i < 64 * 64; i += 256) {
        int ci = i >> 6, q = (i & 63) << 2;
        ushort4 v = *reinterpret_cast<const ushort4*>(abase + (size_t)ci * HH * WW + q);
        *reinterpret_cast<ushort4*>(&a3s[ci][q]) = v;
    }
    __syncthreads();

    const int wu = __builtin_amdgcn_readfirstlane(tid >> 6);  // wave-uniform co group
    const int l  = tid & 63;

    float acc[64];
    #pragma unroll
    for (int i = 0; i < 64; ++i) acc[i] = 0.f;

    #pragma unroll 4
    for (int ci = 0; ci < 64; ++ci) {
        ushort4 raw = *reinterpret_cast<const ushort4*>(&a3s[ci][l << 2]);
        float p0 = bf2f(raw.x), p1 = bf2f(raw.y), p2 = bf2f(raw.z), p3 = bf2f(raw.w);
        #pragma unroll
        for (int j = 0; j < 16; ++j) {
            float wv = pw[(wu * 16 + j) * 64 + ci];   // uniform -> s_load
            acc[j * 4 + 0] = fmaf(wv, p0, acc[j * 4 + 0]);
            acc[j * 4 + 1] = fmaf(wv, p1, acc[j * 4 + 1]);
            acc[j * 4 + 2] = fmaf(wv, p2, acc[j * 4 + 2]);
            acc[j * 4 + 3] = fmaf(wv, p3, acc[j * 4 + 3]);
        }
    }

    #pragma unroll
    for (int j = 0; j < 16; ++j) {
        int co = wu * 16 + j;
        float inv = gamma[co] * rsqrtf(var[co] + 1e-5f);
        float sh  = beta[co] - mean[co] * inv;
        size_t off = (((size_t)b * CC + co) * HH + y) * WW + (l << 2);
        float4 xv = *reinterpret_cast<const float4*>(x + off);
        float4 r;
        float a;
        a = acc[j * 4 + 0] * inv + sh; r.x = xv.x / (1.f + __expf(-a));
        a = acc[j * 4 + 1] * inv + sh; r.y = xv.y / (1.f + __expf(-a));
        a = acc[j * 4 + 2] * inv + sh; r.z = xv.z / (1.f + __expf(-a));
        a = acc[j * 4 + 3] * inv + sh; r.w = xv.w / (1.f + __expf(-a));
        *reinterpret_cast<float4*>(out + off) = r;
    }
}

extern "C" void kernel_launch(void* const* d_in, const int* in_sizes, int n_in,
                              void* d_out, int out_size, void* d_ws, size_t ws_size,
                              hipStream_t stream) {
    const float* x     = (const float*)d_in[0];
    const float* lw    = (const float*)d_in[1];
    const float* hw    = (const float*)d_in[2];
    const float* vw    = (const float*)d_in[3];
    const float* pw    = (const float*)d_in[4];
    const float* gamma = (const float*)d_in[5];
    const float* beta  = (const float*)d_in[6];
    const float* mean  = (const float*)d_in[7];
    const float* var   = (const float*)d_in[8];
    float* out = (float*)d_out;

    // ws: attn2 (bf16) + attn3 (bf16) = 2 * 64 MiB = 128 MiB
    unsigned short* ws1 = (unsigned short*)d_ws;
    unsigned short* ws2 = ws1 + (size_t)BB * CC * HH * WW;

    k1_local_h<<<dim3(HH / 8, BB * CC), 512, 0, stream>>>(x, lw, hw, ws1);
    k2a_v<<<dim3(HH / 32, BB * CC), 256, 0, stream>>>(ws1, vw, ws2);
    k2b_pw<<<dim3(HH, BB), 256, 0, stream>>>(ws2, x, pw, gamma, beta, mean, var, out);
}